// Round 4
// baseline (1014.814 us; speedup 1.0000x reference)
//
#include <hip/hip_runtime.h>
#include <hip/hip_bf16.h>
#include <stdint.h>

#define B_ROWS 32768
#define DIM 512
#define THREADS 512
#define NKT 32              // K-steps of 32 over K=1024
#define ABUF 8192           // 128 rows x 64 B
#define WBUF 24576          // 3 mats x 128 cols x 64 B
#define BUF (ABUF + WBUF)   // 32 KB per stage; x2 = 64 KB -> 2 blocks/CU

typedef __attribute__((ext_vector_type(8))) __bf16 bf16x8;
typedef __attribute__((ext_vector_type(4))) float f32x4;
typedef __attribute__((ext_vector_type(4))) unsigned int uint4v;

__device__ static inline unsigned short f2bf(float f) {
    unsigned int u = __builtin_bit_cast(unsigned int, f);
    u += 0x7fffu + ((u >> 16) & 1u);
    return (unsigned short)(u >> 16);
}

__device__ static inline void load_lds_16B(const void* g, void* lds) {
    __builtin_amdgcn_global_load_lds(
        (const __attribute__((address_space(1))) unsigned int*)g,
        (__attribute__((address_space(3))) unsigned int*)lds,
        16, 0, 0);
}

// Wt2[kt 0..31][t 0..2][n 0..511][64B]: element (t,n,k): kt=k>>5, kc=k&31,
// byte = (kc*2) ^ (((n>>1)&3)<<4). Contiguous 8KB per (kt,t,n-block-of-128).
__global__ void prep_weights(const float* __restrict__ Wu_x, const float* __restrict__ Wu_h,
                             const float* __restrict__ Wr_x, const float* __restrict__ Wr_h,
                             const float* __restrict__ Wc_x, const float* __restrict__ Wc_h,
                             unsigned short* __restrict__ Wt2) {
    __shared__ float tile[32][33];
    const int t = blockIdx.z;
    const int k0 = blockIdx.x * 32;   // multiple of 32 -> kt = k0>>5 fixed
    const int n0 = blockIdx.y * 32;
    const float* Wx = (t == 0) ? Wu_x : (t == 1) ? Wr_x : Wc_x;
    const float* Wh = (t == 0) ? Wu_h : (t == 1) ? Wr_h : Wc_h;
    const int tid = threadIdx.x;
    const int c = tid & 31, r0 = tid >> 5;
#pragma unroll
    for (int i = 0; i < 4; ++i) {
        int kl = r0 + i * 8;
        int k = k0 + kl;
        int n = n0 + c;
        float v = (k < 512) ? Wx[(size_t)k * 512 + n] : Wh[(size_t)(k - 512) * 512 + n];
        tile[kl][c] = v;
    }
    __syncthreads();
    const int kt = k0 >> 5;
#pragma unroll
    for (int i = 0; i < 4; ++i) {
        int nl = r0 + i * 8;
        int kc = c;
        int n = n0 + nl;
        size_t base = (((size_t)kt * 3 + t) * 512 + n) * 64;
        *(unsigned short*)((char*)Wt2 + base + ((kc * 2) ^ (((n >> 1) & 3) << 4))) =
            f2bf(tile[kc][nl]);
    }
}

// Apack[kt 0..31][row 0..32767][64B]: 16B slot s of row r at byte
// (s*16) ^ (((r>>1)&3)<<4). kt<16 from x, else from h.
__global__ __launch_bounds__(512) void prep_A(const float* __restrict__ x,
                                              const float* __restrict__ h,
                                              unsigned short* __restrict__ Apack) {
    const size_t i = (size_t)blockIdx.x * 512 + threadIdx.x;  // 16B chunk id
    const int slot = (int)(i & 3);
    const int row = (int)((i >> 2) & 32767);
    const int kt = (int)(i >> 17);
    const int k0 = kt * 32 + slot * 8;   // 0..1023
    const float* src = (k0 < 512) ? (x + (size_t)row * 512 + k0)
                                  : (h + (size_t)row * 512 + (k0 - 512));
    float4 f0 = *(const float4*)(src + 0);
    float4 f1 = *(const float4*)(src + 4);
    uint4v p;
    p.x = f2bf(f0.x) | ((unsigned)f2bf(f0.y) << 16);
    p.y = f2bf(f0.z) | ((unsigned)f2bf(f0.w) << 16);
    p.z = f2bf(f1.x) | ((unsigned)f2bf(f1.y) << 16);
    p.w = f2bf(f1.z) | ((unsigned)f2bf(f1.w) << 16);
    char* dst = (char*)Apack + (((size_t)kt << 15) + row) * 64
              + ((slot * 16) ^ (((row >> 1) & 3) << 4));
    *(uint4v*)dst = p;
}

// ---------------- main: BK=32, 64KB dbuf, 2 blocks/CU ----------------
__global__ __launch_bounds__(THREADS, 4) void augru_main(
    const float* __restrict__ h, const float* __restrict__ att,
    const unsigned short* __restrict__ Wt2, const unsigned short* __restrict__ Apack,
    const float* __restrict__ bu, const float* __restrict__ br,
    const float* __restrict__ bc, float* __restrict__ out) {
    extern __shared__ char smem[];   // 2 x 32 KB
    const int tid = threadIdx.x;
    const int lane = tid & 63;
    const int wid = tid >> 6;
    const int wm = wid >> 2;   // 0..1
    const int wn = wid & 3;    // 0..3
    const int id = blockIdx.x;
    const int wg = (id & 7) * 128 + (id >> 3);   // XCD-bijective (1024%8==0)
    const int nb = wg & 3;
    const int mb = wg >> 2;
    const int cl = lane & 15;
    const int kg = lane >> 4;

    f32x4 accU[4][2], accR[4][2], accCx[4][2], accCh[4][2];
#pragma unroll
    for (int i = 0; i < 4; ++i)
#pragma unroll
        for (int j = 0; j < 2; ++j) {
            accU[i][j] = (f32x4)(0.f);
            accR[i][j] = (f32x4)(0.f);
            accCx[i][j] = (f32x4)(0.f);
            accCh[i][j] = (f32x4)(0.f);
        }

    auto stage = [&](int buf, int kt) {
        // A: 8 KB contiguous, pre-swizzled: 1 load/thread
        const char* gA = (const char*)Apack + (((size_t)kt << 15) + mb * 128) * 64;
        load_lds_16B(gA + tid * 16, smem + buf * BUF + wid * 1024);
        // W: 24 KB = 3 x 8 KB contiguous, pre-swizzled: 3 loads/thread
#pragma unroll
        for (int it = 0; it < 3; ++it) {
            const char* gW = (const char*)Wt2
                + ((((size_t)kt * 3 + it) * 512 + nb * 128) * 64);
            load_lds_16B(gW + tid * 16,
                         smem + buf * BUF + ABUF + it * 8192 + wid * 1024);
        }
    };

    stage(0, 0);
    __syncthreads();

    for (int kt = 0; kt < NKT; ++kt) {
        const int buf = kt & 1;
        if (kt + 1 < NKT) stage(buf ^ 1, kt + 1);   // max flight before drain
        const char* aB = smem + buf * BUF;
        const char* wB = aB + ABUF;
        bf16x8 a[4];
        bf16x8 bb[3][2];
#pragma unroll
        for (int mi = 0; mi < 4; ++mi) {
            const int row = wm * 64 + mi * 16 + cl;
            a[mi] = __builtin_bit_cast(
                bf16x8, *(const uint4v*)(aB + row * 64
                    + ((kg * 16) ^ (((row >> 1) & 3) << 4))));
        }
#pragma unroll
        for (int t = 0; t < 3; ++t)
#pragma unroll
            for (int ni = 0; ni < 2; ++ni) {
                const int col = wn * 32 + ni * 16 + cl;
                bb[t][ni] = __builtin_bit_cast(
                    bf16x8, *(const uint4v*)(wB + t * 8192 + col * 64
                        + ((kg * 16) ^ (((col >> 1) & 3) << 4))));
            }
        f32x4(&accC)[4][2] = (kt < 16) ? accCx : accCh;
        __builtin_amdgcn_s_setprio(1);
#pragma unroll
        for (int ni = 0; ni < 2; ++ni) {
#pragma unroll
            for (int mi = 0; mi < 4; ++mi)
                accU[mi][ni] = __builtin_amdgcn_mfma_f32_16x16x32_bf16(
                    a[mi], bb[0][ni], accU[mi][ni], 0, 0, 0);
#pragma unroll
            for (int mi = 0; mi < 4; ++mi)
                accR[mi][ni] = __builtin_amdgcn_mfma_f32_16x16x32_bf16(
                    a[mi], bb[1][ni], accR[mi][ni], 0, 0, 0);
#pragma unroll
            for (int mi = 0; mi < 4; ++mi)
                accC[mi][ni] = __builtin_amdgcn_mfma_f32_16x16x32_bf16(
                    a[mi], bb[2][ni], accC[mi][ni], 0, 0, 0);
        }
        __builtin_amdgcn_s_setprio(0);
        __syncthreads();   // drain stage(kt+1) + barrier; other block covers
    }

    // ---- fused epilogue ----
#pragma unroll
    for (int ni = 0; ni < 2; ++ni) {
        const int col = nb * 128 + wn * 32 + ni * 16 + cl;
        const float bU = bu[col];
        const float bR = br[col];
        const float bC = bc[col];
#pragma unroll
        for (int mi = 0; mi < 4; ++mi) {
#pragma unroll
            for (int j = 0; j < 4; ++j) {
                const int row = mb * 128 + wm * 64 + mi * 16 + kg * 4 + j;
                const float up = accU[mi][ni][j] + bU;
                const float rp = accR[mi][ni][j] + bR;
                const float u = 1.f / (1.f + __expf(-up));
                const float r = 1.f / (1.f + __expf(-rp));
                const float cpre = accCx[mi][ni][j] + bC + r * accCh[mi][ni][j];
                const float e = __expf(-2.f * cpre);
                const float cc = (1.f - e) / (1.f + e);   // tanh
                const float aa = att[row];
                const float hv = h[(size_t)row * 512 + col];
                const float u_ = aa * u;
                out[(size_t)row * 512 + col] = (1.f - u_) * hv + u_ * cc;
            }
        }
    }
}

extern "C" void kernel_launch(void* const* d_in, const int* in_sizes, int n_in,
                              void* d_out, int out_size, void* d_ws, size_t ws_size,
                              hipStream_t stream) {
    const float* x    = (const float*)d_in[0];
    const float* h    = (const float*)d_in[1];
    const float* att  = (const float*)d_in[2];
    const float* Wu_x = (const float*)d_in[3];
    const float* bu   = (const float*)d_in[4];
    const float* Wu_h = (const float*)d_in[5];
    const float* Wr_x = (const float*)d_in[6];
    const float* br   = (const float*)d_in[7];
    const float* Wr_h = (const float*)d_in[8];
    const float* Wc_x = (const float*)d_in[9];
    const float* bc   = (const float*)d_in[10];
    const float* Wc_h = (const float*)d_in[11];
    unsigned short* Wt2 = (unsigned short*)d_ws;                        // 3 MB @ 0
    unsigned short* Apack = (unsigned short*)((char*)d_ws + (4 << 20)); // 64 MB @ 4MB
    float* out = (float*)d_out;

    prep_weights<<<dim3(32, 16, 3), 256, 0, stream>>>(Wu_x, Wu_h, Wr_x, Wr_h, Wc_x, Wc_h, Wt2);
    prep_A<<<dim3(8192), 512, 0, stream>>>(x, h, Apack);

    hipFuncSetAttribute((const void*)augru_main,
                        hipFuncAttributeMaxDynamicSharedMemorySize, 2 * BUF);
    augru_main<<<dim3(1024), THREADS, 2 * BUF, stream>>>(
        h, att, Wt2, Apack, bu, br, bc, out);
}

// Round 5
// 149.181 us; speedup vs baseline: 6.8026x; 6.8026x over previous
//
#include <hip/hip_runtime.h>
#include <hip/hip_bf16.h>
#include <stdint.h>

#define B_ROWS 32768
#define DIM 512
#define THREADS 512
#define NKT 32              // K-steps of 32 over K=1024
#define ABUF 8192           // 128 rows x 64 B
#define WBUF 12288          // 3 mats x 64 cols x 64 B
#define BUF (ABUF + WBUF)   // 20 KB per stage; x2 = 40 KB -> 2 blocks/CU

typedef __attribute__((ext_vector_type(8))) __bf16 bf16x8;
typedef __attribute__((ext_vector_type(4))) float f32x4;
typedef __attribute__((ext_vector_type(4))) unsigned int uint4v;

__device__ static inline unsigned short f2bf(float f) {
    unsigned int u = __builtin_bit_cast(unsigned int, f);
    u += 0x7fffu + ((u >> 16) & 1u);
    return (unsigned short)(u >> 16);
}

__device__ static inline void load_lds_16B(const void* g, void* lds) {
    __builtin_amdgcn_global_load_lds(
        (const __attribute__((address_space(1))) unsigned int*)g,
        (__attribute__((address_space(3))) unsigned int*)lds,
        16, 0, 0);
}

// Wt2[kt 0..31][t 0..2][n 0..511][64B]: element (t,n,k): kt=k>>5, kc=k&31,
// byte = (kc*2) ^ (((n>>1)&3)<<4).
__global__ void prep_weights(const float* __restrict__ Wu_x, const float* __restrict__ Wu_h,
                             const float* __restrict__ Wr_x, const float* __restrict__ Wr_h,
                             const float* __restrict__ Wc_x, const float* __restrict__ Wc_h,
                             unsigned short* __restrict__ Wt2) {
    __shared__ float tile[32][33];
    const int t = blockIdx.z;
    const int k0 = blockIdx.x * 32;
    const int n0 = blockIdx.y * 32;
    const float* Wx = (t == 0) ? Wu_x : (t == 1) ? Wr_x : Wc_x;
    const float* Wh = (t == 0) ? Wu_h : (t == 1) ? Wr_h : Wc_h;
    const int tid = threadIdx.x;
    const int c = tid & 31, r0 = tid >> 5;
#pragma unroll
    for (int i = 0; i < 4; ++i) {
        int kl = r0 + i * 8;
        int k = k0 + kl;
        int n = n0 + c;
        float v = (k < 512) ? Wx[(size_t)k * 512 + n] : Wh[(size_t)(k - 512) * 512 + n];
        tile[kl][c] = v;
    }
    __syncthreads();
    const int kt = k0 >> 5;
#pragma unroll
    for (int i = 0; i < 4; ++i) {
        int nl = r0 + i * 8;
        int kc = c;
        int n = n0 + nl;
        size_t base = (((size_t)kt * 3 + t) * 512 + n) * 64;
        *(unsigned short*)((char*)Wt2 + base + ((kc * 2) ^ (((n >> 1) & 3) << 4))) =
            f2bf(tile[kc][nl]);
    }
}

// Apack[kt 0..31][row 0..32767][64B]: 16B slot s of row r at byte
// (s*16) ^ (((r>>1)&3)<<4). kt<16 from x, else from h.
__global__ __launch_bounds__(512) void prep_A(const float* __restrict__ x,
                                              const float* __restrict__ h,
                                              unsigned short* __restrict__ Apack) {
    const size_t i = (size_t)blockIdx.x * 512 + threadIdx.x;  // 16B chunk id
    const int slot = (int)(i & 3);
    const int row = (int)((i >> 2) & 32767);
    const int kt = (int)(i >> 17);
    const int k0 = kt * 32 + slot * 8;   // 0..1023
    const float* src = (k0 < 512) ? (x + (size_t)row * 512 + k0)
                                  : (h + (size_t)row * 512 + (k0 - 512));
    float4 f0 = *(const float4*)(src + 0);
    float4 f1 = *(const float4*)(src + 4);
    uint4v p;
    p.x = f2bf(f0.x) | ((unsigned)f2bf(f0.y) << 16);
    p.y = f2bf(f0.z) | ((unsigned)f2bf(f0.w) << 16);
    p.z = f2bf(f1.x) | ((unsigned)f2bf(f1.y) << 16);
    p.w = f2bf(f1.z) | ((unsigned)f2bf(f1.w) << 16);
    char* dst = (char*)Apack + (((size_t)kt << 15) + row) * 64
              + ((slot * 16) ^ (((row >> 1) & 3) << 4));
    *(uint4v*)dst = p;
}

// ---------------- main: BM=128 BN=64 BK=32, 40KB dbuf, 2 blocks/CU -------------
__global__ __launch_bounds__(THREADS, 4) void augru_main(
    const float* __restrict__ h, const float* __restrict__ att,
    const unsigned short* __restrict__ Wt2, const unsigned short* __restrict__ Apack,
    const float* __restrict__ bu, const float* __restrict__ br,
    const float* __restrict__ bc, float* __restrict__ out) {
    extern __shared__ char smem[];   // 2 x 20 KB
    const int tid = threadIdx.x;
    const int lane = tid & 63;
    const int wid = tid >> 6;
    const int wm = wid >> 2;   // 0..1 -> 64-row half
    const int wn = wid & 3;    // 0..3 -> 16-col slice
    const int id = blockIdx.x;
    const int wg = (id & 7) * 256 + (id >> 3);   // XCD-bijective (2048%8==0)
    const int nb = wg & 7;     // 0..7 -> 64-col block
    const int mb = wg >> 3;    // 0..255
    const int cl = lane & 15;
    const int kg = lane >> 4;

    f32x4 accU[4], accR[4], accCx[4], accCh[4];
#pragma unroll
    for (int i = 0; i < 4; ++i) {
        accU[i] = (f32x4)(0.f);
        accR[i] = (f32x4)(0.f);
        accCx[i] = (f32x4)(0.f);
        accCh[i] = (f32x4)(0.f);
    }

    auto stage = [&](int buf, int kt) {
        // A: 8 KB contiguous, pre-swizzled: 1 load/thread (all 8 waves)
        const char* gA = (const char*)Apack + (((size_t)kt << 15) + (size_t)mb * 128) * 64;
        load_lds_16B(gA + tid * 16, smem + buf * BUF + wid * 1024);
        // W sweep 1: 8 KB covering t=0,1 (all 8 waves)
        {
            const int b = tid * 16;          // 0..8176
            const int t = b >> 12;           // 0 or 1
            const int off = b & 4095;
            const char* gW = (const char*)Wt2
                + (((size_t)kt * 3 + t) * 512 + nb * 64) * 64 + off;
            load_lds_16B(gW, smem + buf * BUF + ABUF + wid * 1024);
        }
        // W sweep 2: 4 KB t=2 (waves 0..3, wave-uniform predicate)
        if (wid < 4) {
            const char* gW = (const char*)Wt2
                + (((size_t)kt * 3 + 2) * 512 + nb * 64) * 64 + tid * 16;
            load_lds_16B(gW, smem + buf * BUF + ABUF + 8192 + wid * 1024);
        }
    };

    stage(0, 0);
    __syncthreads();

    auto body = [&](int kt, f32x4(&accC)[4]) {
        const int buf = kt & 1;
        if (kt + 1 < NKT) stage(buf ^ 1, kt + 1);   // max flight before drain
        const char* aB = smem + buf * BUF;
        const char* wB = aB + ABUF;
        bf16x8 a[4], bb[3];
#pragma unroll
        for (int mi = 0; mi < 4; ++mi) {
            const int row = wm * 64 + mi * 16 + cl;
            a[mi] = __builtin_bit_cast(
                bf16x8, *(const uint4v*)(aB + row * 64
                    + ((kg * 16) ^ (((row >> 1) & 3) << 4))));
        }
        const int col = wn * 16 + cl;   // 0..63 within nb-block
#pragma unroll
        for (int t = 0; t < 3; ++t)
            bb[t] = __builtin_bit_cast(
                bf16x8, *(const uint4v*)(wB + t * 4096 + col * 64
                    + ((kg * 16) ^ (((col >> 1) & 3) << 4))));
        __builtin_amdgcn_s_setprio(1);
#pragma unroll
        for (int mi = 0; mi < 4; ++mi)
            accU[mi] = __builtin_amdgcn_mfma_f32_16x16x32_bf16(
                a[mi], bb[0], accU[mi], 0, 0, 0);
#pragma unroll
        for (int mi = 0; mi < 4; ++mi)
            accR[mi] = __builtin_amdgcn_mfma_f32_16x16x32_bf16(
                a[mi], bb[1], accR[mi], 0, 0, 0);
#pragma unroll
        for (int mi = 0; mi < 4; ++mi)
            accC[mi] = __builtin_amdgcn_mfma_f32_16x16x32_bf16(
                a[mi], bb[2], accC[mi], 0, 0, 0);
        __builtin_amdgcn_s_setprio(0);
        __syncthreads();   // drains stage(kt+1); sibling block covers the stall
    };

    for (int kt = 0; kt < 16; ++kt) body(kt, accCx);   // x-half -> cx
    for (int kt = 16; kt < 32; ++kt) body(kt, accCh);  // h-half -> ch

    // ---- fused epilogue ----
    {
        const int col = nb * 64 + wn * 16 + cl;
        const float bU = bu[col];
        const float bR = br[col];
        const float bC = bc[col];
#pragma unroll
        for (int mi = 0; mi < 4; ++mi) {
#pragma unroll
            for (int j = 0; j < 4; ++j) {
                const int row = mb * 128 + wm * 64 + mi * 16 + kg * 4 + j;
                const float up = accU[mi][j] + bU;
                const float rp = accR[mi][j] + bR;
                const float u = 1.f / (1.f + __expf(-up));
                const float r = 1.f / (1.f + __expf(-rp));
                const float cpre = accCx[mi][j] + bC + r * accCh[mi][j];
                const float e = __expf(-2.f * cpre);
                const float cc = (1.f - e) / (1.f + e);   // tanh
                const float aa = att[row];
                const float hv = h[(size_t)row * 512 + col];
                const float u_ = aa * u;
                out[(size_t)row * 512 + col] = (1.f - u_) * hv + u_ * cc;
            }
        }
    }
}

extern "C" void kernel_launch(void* const* d_in, const int* in_sizes, int n_in,
                              void* d_out, int out_size, void* d_ws, size_t ws_size,
                              hipStream_t stream) {
    const float* x    = (const float*)d_in[0];
    const float* h    = (const float*)d_in[1];
    const float* att  = (const float*)d_in[2];
    const float* Wu_x = (const float*)d_in[3];
    const float* bu   = (const float*)d_in[4];
    const float* Wu_h = (const float*)d_in[5];
    const float* Wr_x = (const float*)d_in[6];
    const float* br   = (const float*)d_in[7];
    const float* Wr_h = (const float*)d_in[8];
    const float* Wc_x = (const float*)d_in[9];
    const float* bc   = (const float*)d_in[10];
    const float* Wc_h = (const float*)d_in[11];
    unsigned short* Wt2 = (unsigned short*)d_ws;                        // 3 MB @ 0
    unsigned short* Apack = (unsigned short*)((char*)d_ws + (4 << 20)); // 64 MB @ 4MB
    float* out = (float*)d_out;

    prep_weights<<<dim3(32, 16, 3), 256, 0, stream>>>(Wu_x, Wu_h, Wr_x, Wr_h, Wc_x, Wc_h, Wt2);
    prep_A<<<dim3(8192), 512, 0, stream>>>(x, h, Apack);

    hipFuncSetAttribute((const void*)augru_main,
                        hipFuncAttributeMaxDynamicSharedMemorySize, 2 * BUF);
    augru_main<<<dim3(2048), THREADS, 2 * BUF, stream>>>(
        h, att, Wt2, Apack, bu, br, bc, out);
}

// Round 6
// 146.660 us; speedup vs baseline: 6.9195x; 1.0172x over previous
//
#include <hip/hip_runtime.h>
#include <hip/hip_bf16.h>
#include <stdint.h>

#define B_ROWS 32768
#define DIM 512
#define THREADS 512
#define NKT 32              // K-steps of 32 over K=1024
#define ABUF 8192           // 128 rows x 64 B
#define WBUF 12288          // 3 mats x 64 cols x 64 B
#define BUF (ABUF + WBUF)   // 20 KB per stage; x3 = 60 KB -> 2 blocks/CU

typedef __attribute__((ext_vector_type(8))) __bf16 bf16x8;
typedef __attribute__((ext_vector_type(4))) float f32x4;
typedef __attribute__((ext_vector_type(4))) unsigned int uint4v;

__device__ static inline unsigned short f2bf(float f) {
    unsigned int u = __builtin_bit_cast(unsigned int, f);
    u += 0x7fffu + ((u >> 16) & 1u);
    return (unsigned short)(u >> 16);
}

__device__ static inline void load_lds_16B(const void* g, void* lds) {
    __builtin_amdgcn_global_load_lds(
        (const __attribute__((address_space(1))) unsigned int*)g,
        (__attribute__((address_space(3))) unsigned int*)lds,
        16, 0, 0);
}

// Wt2[kt 0..31][t 0..2][n 0..511][64B]: element (t,n,k): kt=k>>5, kc=k&31,
// byte = (kc*2) ^ (((n>>1)&3)<<4).
__global__ void prep_weights(const float* __restrict__ Wu_x, const float* __restrict__ Wu_h,
                             const float* __restrict__ Wr_x, const float* __restrict__ Wr_h,
                             const float* __restrict__ Wc_x, const float* __restrict__ Wc_h,
                             unsigned short* __restrict__ Wt2) {
    __shared__ float tile[32][33];
    const int t = blockIdx.z;
    const int k0 = blockIdx.x * 32;
    const int n0 = blockIdx.y * 32;
    const float* Wx = (t == 0) ? Wu_x : (t == 1) ? Wr_x : Wc_x;
    const float* Wh = (t == 0) ? Wu_h : (t == 1) ? Wr_h : Wc_h;
    const int tid = threadIdx.x;
    const int c = tid & 31, r0 = tid >> 5;
#pragma unroll
    for (int i = 0; i < 4; ++i) {
        int kl = r0 + i * 8;
        int k = k0 + kl;
        int n = n0 + c;
        float v = (k < 512) ? Wx[(size_t)k * 512 + n] : Wh[(size_t)(k - 512) * 512 + n];
        tile[kl][c] = v;
    }
    __syncthreads();
    const int kt = k0 >> 5;
#pragma unroll
    for (int i = 0; i < 4; ++i) {
        int nl = r0 + i * 8;
        int kc = c;
        int n = n0 + nl;
        size_t base = (((size_t)kt * 3 + t) * 512 + n) * 64;
        *(unsigned short*)((char*)Wt2 + base + ((kc * 2) ^ (((n >> 1) & 3) << 4))) =
            f2bf(tile[kc][nl]);
    }
}

// Apack[kt 0..31][row 0..32767][64B]: 16B slot s of row r at byte
// (s*16) ^ (((r>>1)&3)<<4). kt<16 from x, else from h.
__global__ __launch_bounds__(512) void prep_A(const float* __restrict__ x,
                                              const float* __restrict__ h,
                                              unsigned short* __restrict__ Apack) {
    const size_t i = (size_t)blockIdx.x * 512 + threadIdx.x;  // 16B chunk id
    const int slot = (int)(i & 3);
    const int row = (int)((i >> 2) & 32767);
    const int kt = (int)(i >> 17);
    const int k0 = kt * 32 + slot * 8;   // 0..1023
    const float* src = (k0 < 512) ? (x + (size_t)row * 512 + k0)
                                  : (h + (size_t)row * 512 + (k0 - 512));
    float4 f0 = *(const float4*)(src + 0);
    float4 f1 = *(const float4*)(src + 4);
    uint4v p;
    p.x = f2bf(f0.x) | ((unsigned)f2bf(f0.y) << 16);
    p.y = f2bf(f0.z) | ((unsigned)f2bf(f0.w) << 16);
    p.z = f2bf(f1.x) | ((unsigned)f2bf(f1.y) << 16);
    p.w = f2bf(f1.z) | ((unsigned)f2bf(f1.w) << 16);
    char* dst = (char*)Apack + (((size_t)kt << 15) + row) * 64
              + ((slot * 16) ^ (((row >> 1) & 3) << 4));
    *(uint4v*)dst = p;
}

// ------- main: BM=128 BN=64 BK=32, triple-buffer + counted vmcnt, 2 blocks/CU --
__global__ __launch_bounds__(THREADS, 4) void augru_main(
    const float* __restrict__ h, const float* __restrict__ att,
    const unsigned short* __restrict__ Wt2, const unsigned short* __restrict__ Apack,
    const float* __restrict__ bu, const float* __restrict__ br,
    const float* __restrict__ bc, float* __restrict__ out) {
    extern __shared__ char smem[];   // 3 x 20 KB
    const int tid = threadIdx.x;
    const int lane = tid & 63;
    const int wid = tid >> 6;
    const int wm = wid >> 2;   // 0..1 -> 64-row half
    const int wn = wid & 3;    // 0..3 -> 16-col slice
    const int id = blockIdx.x;
    const int wg = (id & 7) * 256 + (id >> 3);   // XCD-bijective (2048%8==0)
    const int nb = wg & 7;     // 0..7 -> 64-col block
    const int mb = wg >> 3;    // 0..255
    const int cl = lane & 15;
    const int kg = lane >> 4;

    f32x4 accU[4], accR[4], accCx[4], accCh[4];
#pragma unroll
    for (int i = 0; i < 4; ++i) {
        accU[i] = (f32x4)(0.f);
        accR[i] = (f32x4)(0.f);
        accCx[i] = (f32x4)(0.f);
        accCh[i] = (f32x4)(0.f);
    }

    // Staging: waves 0-3 carry W (3 loads/thread), waves 4-7 carry A (2 loads).
    // Per-wave-uniform load counts -> counted vmcnt is exact.
    auto stage = [&](int buf, int kt) {
        char* base = smem + buf * BUF;
        if (wid < 4) {
            const int i = tid * 16;                  // 0..4080, wave-uniform stride
#pragma unroll
            for (int t = 0; t < 3; ++t) {
                const char* gW = (const char*)Wt2
                    + (((size_t)kt * 3 + t) * 512 + nb * 64) * 64;
                load_lds_16B(gW + i, base + ABUF + t * 4096 + wid * 1024);
            }
        } else {
            const int i = (tid - 256) * 16;          // 0..4080
            const char* gA = (const char*)Apack
                + (((size_t)kt << 15) + (size_t)mb * 128) * 64;
            load_lds_16B(gA + i, base + (wid - 4) * 1024);
            load_lds_16B(gA + 4096 + i, base + 4096 + (wid - 4) * 1024);
        }
    };

    stage(0, 0);
    stage(1, 1);

    auto body = [&](int kt, f32x4(&accC)[4]) {
        if (kt == NKT - 1)
            asm volatile("s_waitcnt vmcnt(0)" ::: "memory");
        else
            asm volatile("s_waitcnt vmcnt(2)" ::: "memory");  // kt's loads done;
                                                              // kt+1's stay in flight
        __builtin_amdgcn_s_barrier();
        if (kt + 2 < NKT) stage((kt + 2) % 3, kt + 2);   // full iter of flight
        const char* aB = smem + (kt % 3) * BUF;
        const char* wB = aB + ABUF;
        bf16x8 a[4], bb[3];
#pragma unroll
        for (int mi = 0; mi < 4; ++mi) {
            const int row = wm * 64 + mi * 16 + cl;
            a[mi] = __builtin_bit_cast(
                bf16x8, *(const uint4v*)(aB + row * 64
                    + ((kg * 16) ^ (((row >> 1) & 3) << 4))));
        }
        const int col = wn * 16 + cl;   // 0..63 within nb-block
#pragma unroll
        for (int t = 0; t < 3; ++t)
            bb[t] = __builtin_bit_cast(
                bf16x8, *(const uint4v*)(wB + t * 4096 + col * 64
                    + ((kg * 16) ^ (((col >> 1) & 3) << 4))));
        __builtin_amdgcn_s_setprio(1);
#pragma unroll
        for (int mi = 0; mi < 4; ++mi)
            accU[mi] = __builtin_amdgcn_mfma_f32_16x16x32_bf16(
                a[mi], bb[0], accU[mi], 0, 0, 0);
#pragma unroll
        for (int mi = 0; mi < 4; ++mi)
            accR[mi] = __builtin_amdgcn_mfma_f32_16x16x32_bf16(
                a[mi], bb[1], accR[mi], 0, 0, 0);
#pragma unroll
        for (int mi = 0; mi < 4; ++mi)
            accC[mi] = __builtin_amdgcn_mfma_f32_16x16x32_bf16(
                a[mi], bb[2], accC[mi], 0, 0, 0);
        __builtin_amdgcn_s_setprio(0);
    };

    for (int kt = 0; kt < 16; ++kt) body(kt, accCx);   // x-half -> cx
    for (int kt = 16; kt < 32; ++kt) body(kt, accCh);  // h-half -> ch

    // ---- fused epilogue ----
    {
        const int col = nb * 64 + wn * 16 + cl;
        const float bU = bu[col];
        const float bR = br[col];
        const float bC = bc[col];
#pragma unroll
        for (int mi = 0; mi < 4; ++mi) {
#pragma unroll
            for (int j = 0; j < 4; ++j) {
                const int row = mb * 128 + wm * 64 + mi * 16 + kg * 4 + j;
                const float up = accU[mi][j] + bU;
                const float rp = accR[mi][j] + bR;
                const float u = 1.f / (1.f + __expf(-up));
                const float r = 1.f / (1.f + __expf(-rp));
                const float cpre = accCx[mi][j] + bC + r * accCh[mi][j];
                const float e = __expf(-2.f * cpre);
                const float cc = (1.f - e) / (1.f + e);   // tanh
                const float aa = att[row];
                const float hv = h[(size_t)row * 512 + col];
                const float u_ = aa * u;
                out[(size_t)row * 512 + col] = (1.f - u_) * hv + u_ * cc;
            }
        }
    }
}

extern "C" void kernel_launch(void* const* d_in, const int* in_sizes, int n_in,
                              void* d_out, int out_size, void* d_ws, size_t ws_size,
                              hipStream_t stream) {
    const float* x    = (const float*)d_in[0];
    const float* h    = (const float*)d_in[1];
    const float* att  = (const float*)d_in[2];
    const float* Wu_x = (const float*)d_in[3];
    const float* bu   = (const float*)d_in[4];
    const float* Wu_h = (const float*)d_in[5];
    const float* Wr_x = (const float*)d_in[6];
    const float* br   = (const float*)d_in[7];
    const float* Wr_h = (const float*)d_in[8];
    const float* Wc_x = (const float*)d_in[9];
    const float* bc   = (const float*)d_in[10];
    const float* Wc_h = (const float*)d_in[11];
    unsigned short* Wt2 = (unsigned short*)d_ws;                        // 3 MB @ 0
    unsigned short* Apack = (unsigned short*)((char*)d_ws + (4 << 20)); // 64 MB @ 4MB
    float* out = (float*)d_out;

    prep_weights<<<dim3(32, 16, 3), 256, 0, stream>>>(Wu_x, Wu_h, Wr_x, Wr_h, Wc_x, Wc_h, Wt2);
    prep_A<<<dim3(8192), 512, 0, stream>>>(x, h, Apack);

    hipFuncSetAttribute((const void*)augru_main,
                        hipFuncAttributeMaxDynamicSharedMemorySize, 3 * BUF);
    augru_main<<<dim3(2048), THREADS, 3 * BUF, stream>>>(
        h, att, Wt2, Apack, bu, br, bc, out);
}